// Round 6
// baseline (162.506 us; speedup 1.0000x reference)
//
#include <hip/hip_runtime.h>

#define NN 10000
#define KK 64
#define CC 128
#define OUTOFF (NN * CC)
#define NA 256        // grid size == split-K blocks for phase A (1 block/CU)
#define CHUNKS_A 625  // 625 * 16 == 10000
#define CHUNKS_C 625  // 16-row chunks for phase C

__device__ __forceinline__ float4 f4fma(float s, float4 v, float4 a) {
    a.x = fmaf(s, v.x, a.x); a.y = fmaf(s, v.y, a.y);
    a.z = fmaf(s, v.z, a.z); a.w = fmaf(s, v.w, a.w);
    return a;
}
__device__ __forceinline__ float4 f4add(float4 a, float4 b) {
    a.x += b.x; a.y += b.y; a.z += b.z; a.w += b.w; return a;
}

// Hand-rolled grid barrier: all NA blocks are co-resident (grid == CU count,
// 1 block/CU at 512 thr / 64 KB LDS), so spinning is deadlock-free.
// Release-add publishes this block's global writes; acquire-load in the poll
// invalidates this CU/XCD's caches before we read other blocks' data.
__device__ __forceinline__ void gridbar(unsigned* cnt, unsigned target) {
    __syncthreads();
    if (threadIdx.x == 0) {
        __hip_atomic_fetch_add(cnt, 1u, __ATOMIC_RELEASE, __HIP_MEMORY_SCOPE_AGENT);
        while (__hip_atomic_load(cnt, __ATOMIC_ACQUIRE, __HIP_MEMORY_SCOPE_AGENT) < target)
            __builtin_amdgcn_s_sleep(2);
    }
    __syncthreads();
}

// ws layout (floats): [0 .. NA*16384)        partials [b][m][k][c]  (16.8 MB)
//                     [NA*16384 .. +16384)   UVW [m][k][c]          (64 KB)
//                     then 2 unsigned counters (memset to 0 each launch)

__global__ __launch_bounds__(512) void fused(
    const float* __restrict__ re, const float* __restrict__ im,
    const float* __restrict__ Qr, const float* __restrict__ Qi,
    const float* __restrict__ Ritz, const int* __restrict__ ldp,
    const float* __restrict__ W, float* __restrict__ ws,
    unsigned* __restrict__ cnt, float* __restrict__ out)
{
    __shared__ float4 smem[4096];   // 64 KB, reused per phase
    const int t = threadIdx.x;
    const int bid = blockIdx.x;

    // ================= Phase A: partial U,V (R4 kA shape: 512 thr, 4x4 tile) =================
    {
        const int kt = t & 15;        // k0 = 4*kt
        const int ctA = t >> 4;       // c0 = 4*ctA (0..31)
        const int row_q = (t & 255) >> 4, q_q = t & 15;
        const int row_x = t >> 5,          q_x = t & 31;
        const float4* gq  = (const float4*)((t < 256) ? Qr : Qi);   // wave-uniform
        const float4* gre = (const float4*)re;
        const float4* gim = (const float4*)im;

        float aU[4][4] = {}, aV[4][4] = {};

        int cb = bid;
        float4 r0 = gq [(size_t)(cb * 16 + row_q) * 16 + q_q];
        float4 r1 = gre[(size_t)(cb * 16 + row_x) * 32 + q_x];
        float4 r2 = gim[(size_t)(cb * 16 + row_x) * 32 + q_x];

        while (true) {
            smem[t] = r0; smem[512 + t] = r1; smem[1024 + t] = r2;
            __syncthreads();
            const int nx = cb + NA;
            if (nx < CHUNKS_A) {
                const int m0 = nx * 16;
                r0 = gq [(size_t)(m0 + row_q) * 16 + q_q];
                r1 = gre[(size_t)(m0 + row_x) * 32 + q_x];
                r2 = gim[(size_t)(m0 + row_x) * 32 + q_x];
            }
#pragma unroll 4
            for (int rr = 0; rr < 16; ++rr) {
                float4 q_r = smem[rr * 16 + kt];
                float4 q_i = smem[256 + rr * 16 + kt];
                float4 x_r = smem[512 + rr * 32 + ctA];
                float4 x_i = smem[1024 + rr * 32 + ctA];
                float qr_[4] = {q_r.x, q_r.y, q_r.z, q_r.w};
                float qi_[4] = {q_i.x, q_i.y, q_i.z, q_i.w};
                float xr_[4] = {x_r.x, x_r.y, x_r.z, x_r.w};
                float xi_[4] = {x_i.x, x_i.y, x_i.z, x_i.w};
#pragma unroll
                for (int a = 0; a < 4; ++a)
#pragma unroll
                    for (int b = 0; b < 4; ++b) {
                        aU[a][b] = fmaf(qr_[a], xr_[b], aU[a][b]);
                        aU[a][b] = fmaf(qi_[a], xi_[b], aU[a][b]);
                        aV[a][b] = fmaf(qi_[a], xr_[b], aV[a][b]);
                        aV[a][b] = fmaf(-qr_[a], xi_[b], aV[a][b]);
                    }
            }
            __syncthreads();
            if (nx >= CHUNKS_A) break;
            cb = nx;
        }
        float* base = ws + (size_t)bid * 16384;
        const int k0 = kt * 4, c0 = ctA * 4;
#pragma unroll
        for (int a = 0; a < 4; ++a) {
            *(float4*)(base + (k0 + a) * CC + c0)        = make_float4(aU[a][0], aU[a][1], aU[a][2], aU[a][3]);
            *(float4*)(base + 8192 + (k0 + a) * CC + c0) = make_float4(aV[a][0], aV[a][1], aV[a][2], aV[a][3]);
        }
    }
    gridbar(cnt + 0, NA);

    // ================= Phase RB: blocks 0..127 reduce one (m,k) row + W-GEMM =================
    if (bid < 128) {
        const int m = bid >> 6, k = bid & 63;
        const int q = t & 31, sl = t >> 5;   // 16 slice lanes, 32 col groups
        const float4* p = (const float4*)ws + (size_t)sl * 4096 + m * 2048 + k * 32 + q;
        float4 z = make_float4(0.f, 0.f, 0.f, 0.f);
        float4 s0 = z, s1 = z, s2 = z, s3 = z;
#pragma unroll
        for (int jj = 0; jj < 4; ++jj) {    // 16 partials/thread, 4 chains
            s0 = f4add(s0, p[0]);
            s1 = f4add(s1, p[(size_t)16 * 4096]);
            s2 = f4add(s2, p[(size_t)32 * 4096]);
            s3 = f4add(s3, p[(size_t)48 * 4096]);
            p += (size_t)64 * 4096;
        }
        smem[t] = f4add(f4add(s0, s1), f4add(s2, s3));   // red4[512]
        __syncthreads();
        float* rowS = (float*)(smem + 512);
        if (t < 32) {
            float4 tot = make_float4(0.f, 0.f, 0.f, 0.f);
#pragma unroll
            for (int g = 0; g < 16; ++g) tot = f4add(tot, smem[g * 32 + t]);
            ((float4*)rowS)[t] = tot;
        }
        __syncthreads();
        if (t < 128) {
            float acc = 0.f;
#pragma unroll 8
            for (int cp = 0; cp < 128; ++cp)
                acc = fmaf(rowS[cp], W[cp * 128 + t], acc);
            const int ld = *ldp;
            const float rz = Ritz[k];
            float tt = 1.f;
            for (int i = 0; i < ld; ++i) tt *= rz;
            ws[(size_t)NA * 16384 + m * 8192 + k * 128 + t] = tt * acc;
        }
        __syncthreads();
    }
    gridbar(cnt + 1, NA);

    // ================= Phase C: res = Q @ UVW + masked-ReLU (R4 kC tile) =================
    {
        const float4* g = (const float4*)(ws + (size_t)NA * 16384);
        for (int i = t; i < 4096; i += 512) smem[i] = g[i];
        __syncthreads();
        // two independent half-block "sub-blocks" grid-stride the 625 chunks
        const int sub = bid * 2 + (t >> 8);     // 0..511
        const int tl = t & 255;
        const int ct = tl & 31;   // float4 col group
        const int r  = tl >> 5;   // 0..7; rows r and r+8 of the chunk

        for (int cb = sub; cb < CHUNKS_C; cb += 512) {
            const int na = cb * 16 + r;
            const int nb = na + 8;
            const float4* qra = (const float4*)(Qr + (size_t)na * KK);
            const float4* qia = (const float4*)(Qi + (size_t)na * KK);
            const float4* qrb = (const float4*)(Qr + (size_t)nb * KK);
            const float4* qib = (const float4*)(Qi + (size_t)nb * KK);

            float4 z = make_float4(0.f, 0.f, 0.f, 0.f);
            float4 Ra = z, Ia = z, Rb = z, Ib = z;

#pragma unroll 4
            for (int k4 = 0; k4 < 16; ++k4) {
                float4 QRa = qra[k4], QIa = qia[k4];
                float4 QRb = qrb[k4], QIb = qib[k4];
                float ar[4] = {QRa.x, QRa.y, QRa.z, QRa.w};
                float ai[4] = {QIa.x, QIa.y, QIa.z, QIa.w};
                float br[4] = {QRb.x, QRb.y, QRb.z, QRb.w};
                float bi[4] = {QIb.x, QIb.y, QIb.z, QIb.w};
#pragma unroll
                for (int j = 0; j < 4; ++j) {
                    const int k = k4 * 4 + j;
                    float4 uw = smem[k * 32 + ct];
                    float4 vw = smem[2048 + k * 32 + ct];
                    Ra = f4fma(ar[j], uw, Ra); Ra = f4fma(ai[j], vw, Ra);
                    Ia = f4fma(ai[j], uw, Ia); Ia = f4fma(-ar[j], vw, Ia);
                    Rb = f4fma(br[j], uw, Rb); Rb = f4fma(bi[j], vw, Rb);
                    Ib = f4fma(bi[j], uw, Ib); Ib = f4fma(-br[j], vw, Ib);
                }
            }
            const int cc = ct * 4;
            {
                float4 rin = *(const float4*)(re + (size_t)na * CC + cc);
                float4 iin = *(const float4*)(im + (size_t)na * CC + cc);
                float4 orr, oii;
                orr.x = rin.x + (Ra.x >= 0.f ? Ra.x : 0.f); oii.x = iin.x + (Ra.x >= 0.f ? Ia.x : 0.f);
                orr.y = rin.y + (Ra.y >= 0.f ? Ra.y : 0.f); oii.y = iin.y + (Ra.y >= 0.f ? Ia.y : 0.f);
                orr.z = rin.z + (Ra.z >= 0.f ? Ra.z : 0.f); oii.z = iin.z + (Ra.z >= 0.f ? Ia.z : 0.f);
                orr.w = rin.w + (Ra.w >= 0.f ? Ra.w : 0.f); oii.w = iin.w + (Ra.w >= 0.f ? Ia.w : 0.f);
                *(float4*)(out + (size_t)na * CC + cc)          = orr;
                *(float4*)(out + OUTOFF + (size_t)na * CC + cc) = oii;
            }
            {
                float4 rin = *(const float4*)(re + (size_t)nb * CC + cc);
                float4 iin = *(const float4*)(im + (size_t)nb * CC + cc);
                float4 orr, oii;
                orr.x = rin.x + (Rb.x >= 0.f ? Rb.x : 0.f); oii.x = iin.x + (Rb.x >= 0.f ? Ib.x : 0.f);
                orr.y = rin.y + (Rb.y >= 0.f ? Rb.y : 0.f); oii.y = iin.y + (Rb.y >= 0.f ? Ib.y : 0.f);
                orr.z = rin.z + (Rb.z >= 0.f ? Rb.z : 0.f); oii.z = iin.z + (Rb.z >= 0.f ? Ib.z : 0.f);
                orr.w = rin.w + (Rb.w >= 0.f ? Rb.w : 0.f); oii.w = iin.w + (Rb.w >= 0.f ? Ib.w : 0.f);
                *(float4*)(out + (size_t)nb * CC + cc)          = orr;
                *(float4*)(out + OUTOFF + (size_t)nb * CC + cc) = oii;
            }
        }
    }
}

extern "C" void kernel_launch(void* const* d_in, const int* in_sizes, int n_in,
                              void* d_out, int out_size, void* d_ws, size_t ws_size,
                              hipStream_t stream) {
    const float* re   = (const float*)d_in[0];
    const float* im   = (const float*)d_in[1];
    const float* Qr   = (const float*)d_in[2];
    const float* Qi   = (const float*)d_in[3];
    const float* Ritz = (const float*)d_in[4];
    const float* W    = (const float*)d_in[5];
    const int*   ldp  = (const int*)d_in[6];
    float* out = (float*)d_out;
    float* ws  = (float*)d_ws;

    unsigned* cnt = (unsigned*)(ws + (size_t)NA * 16384 + 16384);
    hipMemsetAsync((void*)cnt, 0, 16, stream);   // zero both barrier counters

    void* kargs[] = { (void*)&re, (void*)&im, (void*)&Qr, (void*)&Qi,
                      (void*)&Ritz, (void*)&ldp, (void*)&W, (void*)&ws,
                      (void*)&cnt, (void*)&out };
    hipLaunchKernelGGL(fused, dim3(NA), dim3(512), 0, stream,
                       re, im, Qr, Qi, Ritz, ldp, W, ws, cnt, out);
    (void)kargs;
}

// Round 7
// 115.954 us; speedup vs baseline: 1.4015x; 1.4015x over previous
//
#include <hip/hip_runtime.h>

#define NN 10000
#define KK 64
#define CC 128
#define OUTOFF (NN * CC)
#define NA 256        // split-K blocks in kA (1 per CU)
#define ROWS_A 20     // rows per kA chunk
#define CHUNKS_A 500  // 500 * 20 == 10000 exactly

__device__ __forceinline__ float4 f4fma(float s, float4 v, float4 a) {
    a.x = fmaf(s, v.x, a.x); a.y = fmaf(s, v.y, a.y);
    a.z = fmaf(s, v.z, a.z); a.w = fmaf(s, v.w, a.w);
    return a;
}
__device__ __forceinline__ float4 f4add(float4 a, float4 b) {
    a.x += b.x; a.y += b.y; a.z += b.z; a.w += b.w; return a;
}

// ws layout (floats): [0 .. NA*16384)       partials [b][m][k][c]  (16.8 MB)
//                     [NA*16384 .. +16384)  UVW [m][k][c]          (64 KB)

// ---------------- kA: partial U,V = split-K of Q^T X (20-row chunks) ----------------
// Staging regions (float4 units): Qr [0,320) Qi [320,640) re [640,1280) im [1280,1920)
// Each region is row-major contiguous, so flat index f = row*stride + col and the
// global address is gp + n0*stride + f_local.
__global__ __launch_bounds__(512) void kA(const float* __restrict__ re,
                                          const float* __restrict__ im,
                                          const float* __restrict__ Qr,
                                          const float* __restrict__ Qi,
                                          float* __restrict__ part)
{
    __shared__ float4 smem[1920];   // 30 KB
    const int t = threadIdx.x;
    const int bid = blockIdx.x;
    const int kt = t & 15;          // k0 = 4*kt
    const int ct = t >> 4;          // c0 = 4*ct (0..31)

    // Resolve this thread's (up to) 4 staging slots once.
    const float4* gp[4];
    int str[4], rc[4];
#pragma unroll
    for (int s = 0; s < 4; ++s) {
        const int f = t + 512 * s;
        if (f < 320)       { gp[s] = (const float4*)Qr; str[s] = 16; rc[s] = f; }
        else if (f < 640)  { gp[s] = (const float4*)Qi; str[s] = 16; rc[s] = f - 320; }
        else if (f < 1280) { gp[s] = (const float4*)re; str[s] = 32; rc[s] = f - 640; }
        else               { gp[s] = (const float4*)im; str[s] = 32; rc[s] = f - 1280; }
    }
    const bool has3 = (t < 1920 - 1536);

    float aU[4][4] = {}, aV[4][4] = {};

    int cb = bid;
    float4 r0, r1, r2, r3;
    {
        const int n0 = cb * ROWS_A;
        r0 = gp[0][(size_t)n0 * str[0] + rc[0]];
        r1 = gp[1][(size_t)n0 * str[1] + rc[1]];
        r2 = gp[2][(size_t)n0 * str[2] + rc[2]];
        if (has3) r3 = gp[3][(size_t)n0 * str[3] + rc[3]];
    }

    while (true) {
        smem[t] = r0; smem[512 + t] = r1; smem[1024 + t] = r2;
        if (has3) smem[1536 + t] = r3;
        __syncthreads();
        const int nx = cb + NA;
        if (nx < CHUNKS_A) {   // prefetch next chunk into registers during compute
            const int n0 = nx * ROWS_A;
            r0 = gp[0][(size_t)n0 * str[0] + rc[0]];
            r1 = gp[1][(size_t)n0 * str[1] + rc[1]];
            r2 = gp[2][(size_t)n0 * str[2] + rc[2]];
            if (has3) r3 = gp[3][(size_t)n0 * str[3] + rc[3]];
        }
#pragma unroll 4
        for (int rr = 0; rr < ROWS_A; ++rr) {
            float4 q_r = smem[rr * 16 + kt];
            float4 q_i = smem[320 + rr * 16 + kt];
            float4 x_r = smem[640 + rr * 32 + ct];
            float4 x_i = smem[1280 + rr * 32 + ct];
            float qr_[4] = {q_r.x, q_r.y, q_r.z, q_r.w};
            float qi_[4] = {q_i.x, q_i.y, q_i.z, q_i.w};
            float xr_[4] = {x_r.x, x_r.y, x_r.z, x_r.w};
            float xi_[4] = {x_i.x, x_i.y, x_i.z, x_i.w};
#pragma unroll
            for (int a = 0; a < 4; ++a)
#pragma unroll
                for (int b = 0; b < 4; ++b) {
                    aU[a][b] = fmaf(qr_[a], xr_[b], aU[a][b]);
                    aU[a][b] = fmaf(qi_[a], xi_[b], aU[a][b]);
                    aV[a][b] = fmaf(qi_[a], xr_[b], aV[a][b]);
                    aV[a][b] = fmaf(-qr_[a], xi_[b], aV[a][b]);
                }
        }
        __syncthreads();
        if (nx >= CHUNKS_A) break;
        cb = nx;
    }
    float* base = part + (size_t)bid * 16384;
    const int k0 = kt * 4, c0 = ct * 4;
#pragma unroll
    for (int a = 0; a < 4; ++a) {
        *(float4*)(base + (k0 + a) * CC + c0)        = make_float4(aU[a][0], aU[a][1], aU[a][2], aU[a][3]);
        *(float4*)(base + 8192 + (k0 + a) * CC + c0) = make_float4(aV[a][0], aV[a][1], aV[a][2], aV[a][3]);
    }
}

// ---------------- kRB: reduce 256 partials -> row, then UVW = TT * row @ W ----------------
// grid 128 = (m in {U,V}) x (k in 0..63); 512 threads; float4 loads, 4 chains x 4 rounds
__global__ __launch_bounds__(512) void kRB(const float* __restrict__ part,
                                           const float* __restrict__ Ritz,
                                           const int* __restrict__ ldp,
                                           const float* __restrict__ W,
                                           float* __restrict__ UVW)
{
    __shared__ float4 red4[512];
    __shared__ float rowS[128];
    const int t = threadIdx.x;
    const int m = blockIdx.x >> 6, k = blockIdx.x & 63;
    const int q = t & 31, sl = t >> 5;   // 16 slice lanes, 32 col groups

    const float4* p = (const float4*)part + (size_t)sl * 4096 + m * 2048 + k * 32 + q;
    float4 z = make_float4(0.f, 0.f, 0.f, 0.f);
    float4 s0 = z, s1 = z, s2 = z, s3 = z;
#pragma unroll
    for (int jj = 0; jj < 4; ++jj) {     // 16 partials/thread, 4 independent chains
        s0 = f4add(s0, p[0]);
        s1 = f4add(s1, p[(size_t)16 * 4096]);
        s2 = f4add(s2, p[(size_t)32 * 4096]);
        s3 = f4add(s3, p[(size_t)48 * 4096]);
        p += (size_t)64 * 4096;
    }
    red4[t] = f4add(f4add(s0, s1), f4add(s2, s3));
    __syncthreads();
    if (t < 32) {
        float4 tot = z;
#pragma unroll
        for (int g = 0; g < 16; ++g) tot = f4add(tot, red4[g * 32 + t]);
        ((float4*)rowS)[t] = tot;
    }
    __syncthreads();
    if (t < 128) {
        float acc = 0.f;
#pragma unroll 8
        for (int cp = 0; cp < 128; ++cp)
            acc = fmaf(rowS[cp], W[cp * 128 + t], acc);
        const int ld = *ldp;
        const float rz = Ritz[k];
        float tt = 1.f;
        for (int i = 0; i < ld; ++i) tt *= rz;
        UVW[m * 8192 + k * 128 + t] = tt * acc;
    }
}

// ---------------- kC: res = Q @ UVW + masked-ReLU epilogue ----------------
// 625 blocks x 256 threads, 16 rows/block (exact). Thread = 2 rows x 4 cols.
__global__ __launch_bounds__(256) void kC(const float* __restrict__ re,
                                          const float* __restrict__ im,
                                          const float* __restrict__ Qr,
                                          const float* __restrict__ Qi,
                                          const float* __restrict__ UVW,
                                          float* __restrict__ out)
{
    __shared__ float4 s[4096];   // [0..2047] UW [k][c4], [2048..4095] VW [k][c4]
    const int t = threadIdx.x;
    {
        const float4* g = (const float4*)UVW;
        for (int i = t; i < 4096; i += 256) s[i] = g[i];
    }
    __syncthreads();
    const int ct = t & 31;   // float4 col group: cols 4*ct..+3
    const int r  = t >> 5;   // 0..7
    const int na = blockIdx.x * 16 + r;      // rows na and na+8; 625*16==10000
    const int nb = na + 8;

    const float4* qra = (const float4*)(Qr + (size_t)na * KK);
    const float4* qia = (const float4*)(Qi + (size_t)na * KK);
    const float4* qrb = (const float4*)(Qr + (size_t)nb * KK);
    const float4* qib = (const float4*)(Qi + (size_t)nb * KK);

    float4 z = make_float4(0.f, 0.f, 0.f, 0.f);
    float4 Ra = z, Ia = z, Rb = z, Ib = z;

#pragma unroll 4
    for (int k4 = 0; k4 < 16; ++k4) {
        float4 QRa = qra[k4], QIa = qia[k4];
        float4 QRb = qrb[k4], QIb = qib[k4];
        float ar[4] = {QRa.x, QRa.y, QRa.z, QRa.w};
        float ai[4] = {QIa.x, QIa.y, QIa.z, QIa.w};
        float br[4] = {QRb.x, QRb.y, QRb.z, QRb.w};
        float bi[4] = {QIb.x, QIb.y, QIb.z, QIb.w};
#pragma unroll
        for (int j = 0; j < 4; ++j) {
            const int k = k4 * 4 + j;
            float4 uw = s[k * 32 + ct];
            float4 vw = s[2048 + k * 32 + ct];
            Ra = f4fma(ar[j], uw, Ra); Ra = f4fma(ai[j], vw, Ra);
            Ia = f4fma(ai[j], uw, Ia); Ia = f4fma(-ar[j], vw, Ia);
            Rb = f4fma(br[j], uw, Rb); Rb = f4fma(bi[j], vw, Rb);
            Ib = f4fma(bi[j], uw, Ib); Ib = f4fma(-br[j], vw, Ib);
        }
    }
    const int cc = ct * 4;
    {
        float4 rin = *(const float4*)(re + (size_t)na * CC + cc);
        float4 iin = *(const float4*)(im + (size_t)na * CC + cc);
        float4 orr, oii;
        orr.x = rin.x + (Ra.x >= 0.f ? Ra.x : 0.f); oii.x = iin.x + (Ra.x >= 0.f ? Ia.x : 0.f);
        orr.y = rin.y + (Ra.y >= 0.f ? Ra.y : 0.f); oii.y = iin.y + (Ra.y >= 0.f ? Ia.y : 0.f);
        orr.z = rin.z + (Ra.z >= 0.f ? Ra.z : 0.f); oii.z = iin.z + (Ra.z >= 0.f ? Ia.z : 0.f);
        orr.w = rin.w + (Ra.w >= 0.f ? Ra.w : 0.f); oii.w = iin.w + (Ra.w >= 0.f ? Ia.w : 0.f);
        *(float4*)(out + (size_t)na * CC + cc)          = orr;
        *(float4*)(out + OUTOFF + (size_t)na * CC + cc) = oii;
    }
    {
        float4 rin = *(const float4*)(re + (size_t)nb * CC + cc);
        float4 iin = *(const float4*)(im + (size_t)nb * CC + cc);
        float4 orr, oii;
        orr.x = rin.x + (Rb.x >= 0.f ? Rb.x : 0.f); oii.x = iin.x + (Rb.x >= 0.f ? Ib.x : 0.f);
        orr.y = rin.y + (Rb.y >= 0.f ? Rb.y : 0.f); oii.y = iin.y + (Rb.y >= 0.f ? Ib.y : 0.f);
        orr.z = rin.z + (Rb.z >= 0.f ? Rb.z : 0.f); oii.z = iin.z + (Rb.z >= 0.f ? Ib.z : 0.f);
        orr.w = rin.w + (Rb.w >= 0.f ? Rb.w : 0.f); oii.w = iin.w + (Rb.w >= 0.f ? Ib.w : 0.f);
        *(float4*)(out + (size_t)nb * CC + cc)          = orr;
        *(float4*)(out + OUTOFF + (size_t)nb * CC + cc) = oii;
    }
}

extern "C" void kernel_launch(void* const* d_in, const int* in_sizes, int n_in,
                              void* d_out, int out_size, void* d_ws, size_t ws_size,
                              hipStream_t stream) {
    const float* re   = (const float*)d_in[0];
    const float* im   = (const float*)d_in[1];
    const float* Qr   = (const float*)d_in[2];
    const float* Qi   = (const float*)d_in[3];
    const float* Ritz = (const float*)d_in[4];
    const float* W    = (const float*)d_in[5];
    const int*   ldp  = (const int*)d_in[6];
    float* out = (float*)d_out;
    float* ws  = (float*)d_ws;

    float* part = ws;                          // NA * 16384 floats
    float* UVW  = ws + (size_t)NA * 16384;     // 16384 floats

    kA <<<NA,  512, 0, stream>>>(re, im, Qr, Qi, part);
    kRB<<<128, 512, 0, stream>>>(part, Ritz, ldp, W, UVW);
    kC <<<625, 256, 0, stream>>>(re, im, Qr, Qi, UVW, out);
}